// Round 3
// baseline (4810.876 us; speedup 1.0000x reference)
//
#include <hip/hip_runtime.h>
#include <hip/hip_bf16.h>
#include <cstdint>
#include <cstddef>

typedef __attribute__((ext_vector_type(8))) __bf16 bf16x8;
typedef __attribute__((ext_vector_type(4))) __bf16 bf16x4;
typedef __attribute__((ext_vector_type(4))) float floatx4;
typedef __attribute__((ext_vector_type(16))) float floatx16;

__device__ __forceinline__ floatx4 mfma16(bf16x8 a, bf16x8 b, floatx4 c) {
  return __builtin_amdgcn_mfma_f32_16x16x32_bf16(a, b, c, 0, 0, 0);
}
__device__ __forceinline__ floatx16 mfma32(bf16x8 a, bf16x8 b, floatx16 c) {
  return __builtin_amdgcn_mfma_f32_32x32x16_bf16(a, b, c, 0, 0, 0);
}

__device__ __forceinline__ float tanh_fast(float x) {
  float e = __expf(2.0f * x);
  return 1.0f - 2.0f / (e + 1.0f);
}

// Coherent (MALL-level) bf16 store: sc0 sc1 = write-through past L1/L2.
__device__ __forceinline__ void store_coh_bf16(__bf16* p, float f) {
  unsigned v = (unsigned)__builtin_bit_cast(unsigned short, (__bf16)f);
  asm volatile("global_store_short %0, %1, off sc0 sc1" :: "v"(p), "v"(v));
}

// Coherent 16B store (one dwordx4, write-through to MALL).
__device__ __forceinline__ void store_coh_b128(__bf16* p, bf16x8 v) {
  asm volatile("global_store_dwordx4 %0, %1, off sc0 sc1" :: "v"(p), "v"(v) : "memory");
}

// Issue 4 coherent 16B loads (no wait). Valid only after a coh_wait.
__device__ __forceinline__ void coh_load4(const char* p, bf16x8& a, bf16x8& b,
                                          bf16x8& c, bf16x8& d) {
  asm volatile(
      "global_load_dwordx4 %0, %4, off offset:-4096 sc0 sc1\n\t"
      "global_load_dwordx4 %1, %4, off sc0 sc1\n\t"
      "global_load_dwordx4 %2, %5, off offset:-4096 sc0 sc1\n\t"
      "global_load_dwordx4 %3, %5, off sc0 sc1"
      : "=v"(a), "=v"(b), "=v"(c), "=v"(d)
      : "v"(p), "v"(p + 8192)
      : "memory");
}

__device__ __forceinline__ void coh_wait8(bf16x8& a, bf16x8& b, bf16x8& c, bf16x8& d,
                                          bf16x8& e, bf16x8& f, bf16x8& g, bf16x8& h) {
  asm volatile("s_waitcnt vmcnt(0)"
               : "+v"(a), "+v"(b), "+v"(c), "+v"(d),
                 "+v"(e), "+v"(f), "+v"(g), "+v"(h)
               :
               : "memory");
}

// Counted wait: allow the newest 8 loads to remain in flight. With 16 staging
// loads (+ at most one earlier xp prefetch) outstanding, this guarantees the
// oldest half (s0..s7) has landed in any issue interleave.
__device__ __forceinline__ void coh_wait8_vm8(bf16x8& a, bf16x8& b, bf16x8& c, bf16x8& d,
                                              bf16x8& e, bf16x8& f, bf16x8& g, bf16x8& h) {
  asm volatile("s_waitcnt vmcnt(8)"
               : "+v"(a), "+v"(b), "+v"(c), "+v"(d),
                 "+v"(e), "+v"(f), "+v"(g), "+v"(h)
               :
               : "memory");
}

// ---------------------------------------------------------------------------
__global__ __launch_bounds__(256) void k_cvt(const float* __restrict__ src,
                                             __bf16* __restrict__ dst, int n8) {
  int i = blockIdx.x * 256 + threadIdx.x;
  const int stride = gridDim.x * 256;
  for (; i < n8; i += stride) {
    const float4* s = (const float4*)(src + (size_t)i * 8);
    float4 a = s[0], b = s[1];
    bf16x8 v;
    v[0] = (__bf16)a.x; v[1] = (__bf16)a.y; v[2] = (__bf16)a.z; v[3] = (__bf16)a.w;
    v[4] = (__bf16)b.x; v[5] = (__bf16)b.y; v[6] = (__bf16)b.z; v[7] = (__bf16)b.w;
    *(bf16x8*)(dst + (size_t)i * 8) = v;
  }
}

// ---------------------------------------------------------------------------
// k_xp: xp[t][m][n] = sum_i x[m][t][i] * Wx[n][i]  (bf16 out, t-major so the
// RNN reads one contiguous slab per step). Block = (t, 32-row m-tile),
// A staged fp32->bf16 in LDS then held in registers; 16 column passes of 64.
// ---------------------------------------------------------------------------
__global__ __launch_bounds__(256) void k_xp(
    const float* __restrict__ x,      // [128][1024][512] f32
    const __bf16* __restrict__ wihb,  // [1024][1536] bf16
    __bf16* __restrict__ xp)          // [1024][128][1024] bf16
{
  __shared__ __align__(16) __bf16 xls[32 * 520];  // 32 rows x (512+8 pad)
  __shared__ __align__(16) __bf16 st[32 * 72];    // store-staging 32 x (64+8)

  const int tid = threadIdx.x;
  const int t   = blockIdx.x >> 2;
  const int mt  = blockIdx.x & 3;

  // stage x[mt*32..+31][t][0..511] -> LDS (bf16)
  {
    const int r = tid >> 3, c = tid & 7;
    const float* xs = x + ((size_t)(mt * 32 + r) * 1024 + t) * 512 + c * 4;
#pragma unroll
    for (int it = 0; it < 16; ++it) {
      float4 v = *(const float4*)(xs + it * 32);
      bf16x4 b;
      b[0] = (__bf16)v.x; b[1] = (__bf16)v.y; b[2] = (__bf16)v.z; b[3] = (__bf16)v.w;
      *(bf16x4*)(xls + r * 520 + it * 32 + c * 4) = b;
    }
  }
  __syncthreads();

  const int lane = tid & 63, w = tid >> 6;
  const int lm = lane & 15, q = lane >> 4, qk = q * 8;

  // A fragments (rows lm, lm+16) -> registers, reused across all 16 passes
  bf16x8 a0[16], a1[16];
#pragma unroll
  for (int kk = 0; kk < 16; ++kk) {
    a0[kk] = *(const bf16x8*)(xls + lm * 520 + kk * 32 + qk);
    a1[kk] = *(const bf16x8*)(xls + (16 + lm) * 520 + kk * 32 + qk);
  }

  const int row = tid >> 3, ch = tid & 7;
  for (int pass = 0; pass < 16; ++pass) {
    const int n = pass * 64 + w * 16 + lm;
    const __bf16* bp = wihb + (size_t)n * 1536 + qk;   // Wx row n
    floatx4 acc0 = {0.f, 0.f, 0.f, 0.f};
    floatx4 acc1 = {0.f, 0.f, 0.f, 0.f};
#pragma unroll
    for (int kk = 0; kk < 16; ++kk) {
      bf16x8 b = *(const bf16x8*)(bp + kk * 32);
      acc0 = mfma16(a0[kk], b, acc0);
      acc1 = mfma16(a1[kk], b, acc1);
    }
    __syncthreads();                    // prior pass's st reads complete
#pragma unroll
    for (int r = 0; r < 4; ++r) {
      st[(q * 4 + r) * 72 + w * 16 + lm]      = (__bf16)acc0[r];
      st[(16 + q * 4 + r) * 72 + w * 16 + lm] = (__bf16)acc1[r];
    }
    __syncthreads();
    bf16x8 v = *(const bf16x8*)(st + row * 72 + ch * 8);
    *(bf16x8*)(xp + ((size_t)t * 128 + mt * 32 + row) * 1024 + pass * 64 + ch * 8) = v;
  }
}

// ---------------------------------------------------------------------------
// k_rnn2: xp-fed recurrence. 4 groups x 16 col-blocks (64 cols), 64 blocks,
// 1/CU. Per block: Wh fragments register-resident for the whole loop (wave w
// owns K-slice [w*256, w*256+256), all 64 cols, mfma 32x32x16); hs read
// exactly once per CU per step; cross-wave K-reduction in a SEPARATE LDS
// buffer; staging split with counted vmcnt; one 16B coherent store/thread.
// Barrier protocol: PER-WAVE signaling. Each wave drains its own coherent
// stores (vmcnt(0)) then lane 0 increments ct[w]; detector polls the 4
// per-wave counters for >= t*16. This removes the end-of-step block barrier
// from the serial chain. Safety: part is a separate buffer, and all step-t+1
// hs/part writes are ordered behind t+1's detect/staging __syncthreads,
// which every wave reaches only after its step-t reads.
// Static LDS: 66,048 + 34,816 = 100,864 B (1 block/CU of 160 KB).
// ---------------------------------------------------------------------------
__global__ __launch_bounds__(256, 1) void k_rnn2(
    const __bf16* __restrict__ xp,      // [1024][128][1024]
    const __bf16* __restrict__ wihb,    // [1024][1536]
    const float*  __restrict__ bih,     // [1024]
    __bf16* __restrict__ h0,
    __bf16* __restrict__ h1,
    unsigned* __restrict__ cnt)
{
  __shared__ __align__(16) __bf16 hs[32 * 1032];    // 66,048 B
  __shared__ __align__(16) float part[4 * 32 * 68]; // 34,816 B

  const int tid  = threadIdx.x;
  const int lane = tid & 63;
  const int w    = tid >> 6;
  const int g    = blockIdx.x >> 4;
  const int cb   = blockIdx.x & 15;
  const int l31  = lane & 31;
  const int l5   = lane >> 5;
  const int r0   = g * 32;
  const int n0   = cb * 64;
  unsigned* ct = cnt + g * 32;          // ct[0..3] = per-wave counters

  // Wh fragments resident in registers: wave w covers k in [w*256, w*256+256)
  bf16x8 wh0[16], wh1[16];
  {
    const __bf16* wp = wihb + (size_t)(n0 + l31) * 1536 + 512 + w * 256 + l5 * 8;
#pragma unroll
    for (int s = 0; s < 16; ++s) {
      wh0[s] = *(const bf16x8*)(wp + s * 16);              // cols n0..n0+31
      wh1[s] = *(const bf16x8*)(wp + 32 * 1536 + s * 16);  // cols n0+32..n0+63
    }
  }

  const int erow = tid >> 3;           // epilogue row 0..31
  const int ec0  = (tid & 7) * 8;      // epilogue col-chunk base
  const floatx4 bia = *(const floatx4*)(bih + n0 + ec0);
  const floatx4 bib = *(const floatx4*)(bih + n0 + ec0 + 4);

  __bf16* sdst = hs + (tid >> 7) * 1032 + (tid & 127) * 8;
  const int koff = w * 256 + l5 * 8;

  for (int t = 0; t < 1024; ++t) {
    // prefetch this step's xp slice (precomputed; valid any time)
    bf16x8 xpv = *(const bf16x8*)(xp + ((size_t)t * 128 + r0 + erow) * 1024 + n0 + ec0);

    floatx16 accA = (floatx16)0.0f;
    floatx16 accB = (floatx16)0.0f;

    if (t > 0) {
      // ---- wait: all 64 waves of this group finished step t-1
      if (tid == 0) {
        const unsigned target = (unsigned)t * 16u;
        for (;;) {
          unsigned c0 = __hip_atomic_load(ct + 0, __ATOMIC_RELAXED, __HIP_MEMORY_SCOPE_AGENT);
          unsigned c1 = __hip_atomic_load(ct + 1, __ATOMIC_RELAXED, __HIP_MEMORY_SCOPE_AGENT);
          unsigned c2 = __hip_atomic_load(ct + 2, __ATOMIC_RELAXED, __HIP_MEMORY_SCOPE_AGENT);
          unsigned c3 = __hip_atomic_load(ct + 3, __ATOMIC_RELAXED, __HIP_MEMORY_SCOPE_AGENT);
          if (c0 >= target && c1 >= target && c2 >= target && c3 >= target) break;
          __builtin_amdgcn_s_sleep(1);
        }
      }
      __syncthreads();

      // stage h_t rows r0..r0+31 -> LDS (coherent, bulk-issued, split drain)
      {
        const __bf16* hc = (t & 1) ? h1 : h0;
        const char* base = (const char*)(hc + (size_t)r0 * 1024) + tid * 16 + 4096;
        bf16x8 s0,s1,s2,s3,s4,s5,s6,s7,s8,s9,s10,s11,s12,s13,s14,s15;
        coh_load4(base,         s0, s1, s2, s3);
        coh_load4(base + 16384, s4, s5, s6, s7);
        coh_load4(base + 32768, s8, s9, s10, s11);
        coh_load4(base + 49152, s12, s13, s14, s15);
        coh_wait8_vm8(s0, s1, s2, s3, s4, s5, s6, s7);   // front half landed
        *(bf16x8*)(sdst +  0 * 2064) = s0;  *(bf16x8*)(sdst +  1 * 2064) = s1;
        *(bf16x8*)(sdst +  2 * 2064) = s2;  *(bf16x8*)(sdst +  3 * 2064) = s3;
        *(bf16x8*)(sdst +  4 * 2064) = s4;  *(bf16x8*)(sdst +  5 * 2064) = s5;
        *(bf16x8*)(sdst +  6 * 2064) = s6;  *(bf16x8*)(sdst +  7 * 2064) = s7;
        coh_wait8(s8, s9, s10, s11, s12, s13, s14, s15); // back half
        *(bf16x8*)(sdst +  8 * 2064) = s8;  *(bf16x8*)(sdst +  9 * 2064) = s9;
        *(bf16x8*)(sdst + 10 * 2064) = s10; *(bf16x8*)(sdst + 11 * 2064) = s11;
        *(bf16x8*)(sdst + 12 * 2064) = s12; *(bf16x8*)(sdst + 13 * 2064) = s13;
        *(bf16x8*)(sdst + 14 * 2064) = s14; *(bf16x8*)(sdst + 15 * 2064) = s15;
      }
      __syncthreads();

      // K-split h-matmul: weights in regs, hs read once per CU per step
#pragma unroll
      for (int s = 0; s < 16; ++s) {
        bf16x8 a = *(const bf16x8*)(hs + l31 * 1032 + koff + s * 16);
        accA = mfma32(a, wh0[s], accA);
        accB = mfma32(a, wh1[s], accB);
      }
    }

    // write partial sums (separate buffer -> no barrier needed before this;
    // prior-step part reads were sealed by this step's staging barrier)
#pragma unroll
    for (int r = 0; r < 16; ++r) {
      const int prow = (r & 3) + 8 * (r >> 2) + 4 * l5;   // C/D row map
      part[(size_t)(w * 32 + prow) * 68 + l31]      = accA[r];
      part[(size_t)(w * 32 + prow) * 68 + 32 + l31] = accB[r];
    }
    __syncthreads();

    // epilogue: reduce 4 partials + xp + bias, tanh, one 16B coherent store
    {
      floatx4 sa = (floatx4)0.0f, sb = (floatx4)0.0f;
#pragma unroll
      for (int w2 = 0; w2 < 4; ++w2) {
        const float* pp = part + (size_t)(w2 * 32 + erow) * 68 + ec0;
        sa += *(const floatx4*)pp;
        sb += *(const floatx4*)(pp + 4);
      }
      bf16x8 res;
#pragma unroll
      for (int j = 0; j < 4; ++j) {
        res[j]     = (__bf16)tanh_fast(sa[j] + bia[j] + (float)xpv[j]);
        res[j + 4] = (__bf16)tanh_fast(sb[j] + bib[j] + (float)xpv[j + 4]);
      }
      __bf16* hn = (t & 1) ? h0 : h1;
      store_coh_b128(hn + (size_t)(r0 + erow) * 1024 + n0 + ec0, res);
    }
    // per-wave signal: drain own coherent stores, then lane 0 increments ct[w]
    asm volatile("s_waitcnt vmcnt(0)" ::: "memory");
    if (lane == 0)
      __hip_atomic_fetch_add(ct + w, 1u, __ATOMIC_RELAXED, __HIP_MEMORY_SCOPE_AGENT);
  }
  // h_1024 lands in h0 (t=1023 writes hn=h0)
}

// ---------------------------------------------------------------------------
// Fallback (previously verified) recurrence kernel — used when ws is small.
// ---------------------------------------------------------------------------
__global__ __launch_bounds__(256) void k_rnn(
    const __bf16* __restrict__ xb,      // [128][1024][512]
    const __bf16* __restrict__ wihb,    // [1024][1536]
    const float*  __restrict__ bih,     // [1024]
    __bf16* __restrict__ h0,
    __bf16* __restrict__ h1,
    unsigned* __restrict__ cnt)
{
  __shared__ __bf16 hs[32 * 1032];

  const int tid  = threadIdx.x;
  const int lane = tid & 63;
  const int w    = tid >> 6;
  const int g    = blockIdx.x >> 4;
  const int cb   = blockIdx.x & 15;
  const int lm   = lane & 15;
  const int q    = lane >> 4;
  const int qk   = q * 8;
  const int wc   = cb * 64 + w * 16;
  const int n    = wc + lm;
  const int r0   = g * 32;

  const __bf16* bxp = wihb + (size_t)n * 1536 + qk;
  const __bf16* bhp = bxp + 512;
  const float bias = bih[n];
  unsigned* ct = cnt + g * 16;

  const __bf16* xr0 = xb + (size_t)(r0 + lm) * 524288 + qk;
  const __bf16* xr1 = xr0 + 16ull * 524288;

  __bf16* sdst = hs + (tid >> 7) * 1032 + (tid & 127) * 8;

  for (int t = 0; t < 1024; ++t) {
    floatx4 acc0 = {0.f, 0.f, 0.f, 0.f};
    floatx4 acc1 = {0.f, 0.f, 0.f, 0.f};

    {
      const __bf16* xa0 = xr0 + (size_t)t * 512;
      const __bf16* xa1 = xr1 + (size_t)t * 512;
#pragma unroll 4
      for (int kk = 0; kk < 16; ++kk) {
        bf16x8 b = *(const bf16x8*)(bxp + kk * 32);
        acc0 = mfma16(*(const bf16x8*)(xa0 + kk * 32), b, acc0);
        acc1 = mfma16(*(const bf16x8*)(xa1 + kk * 32), b, acc1);
      }
    }

    if (t > 0) {
      if (tid == 0) {
        const unsigned target = (unsigned)t * 16u;
        while (__hip_atomic_load(ct, __ATOMIC_RELAXED, __HIP_MEMORY_SCOPE_AGENT) < target)
          __builtin_amdgcn_s_sleep(1);
      }
      __syncthreads();

      {
        const __bf16* hc = (t & 1) ? h1 : h0;
        const char* base = (const char*)(hc + (size_t)r0 * 1024) + tid * 16 + 4096;
        bf16x8 s0,s1,s2,s3,s4,s5,s6,s7,s8,s9,s10,s11,s12,s13,s14,s15;
        coh_load4(base,         s0, s1, s2, s3);
        coh_load4(base + 16384, s4, s5, s6, s7);
        coh_load4(base + 32768, s8, s9, s10, s11);
        coh_load4(base + 49152, s12, s13, s14, s15);
        coh_wait8(s0, s1, s2, s3, s4, s5, s6, s7);
        coh_wait8(s8, s9, s10, s11, s12, s13, s14, s15);
        *(bf16x8*)(sdst +  0 * 2064) = s0;  *(bf16x8*)(sdst +  1 * 2064) = s1;
        *(bf16x8*)(sdst +  2 * 2064) = s2;  *(bf16x8*)(sdst +  3 * 2064) = s3;
        *(bf16x8*)(sdst +  4 * 2064) = s4;  *(bf16x8*)(sdst +  5 * 2064) = s5;
        *(bf16x8*)(sdst +  6 * 2064) = s6;  *(bf16x8*)(sdst +  7 * 2064) = s7;
        *(bf16x8*)(sdst +  8 * 2064) = s8;  *(bf16x8*)(sdst +  9 * 2064) = s9;
        *(bf16x8*)(sdst + 10 * 2064) = s10; *(bf16x8*)(sdst + 11 * 2064) = s11;
        *(bf16x8*)(sdst + 12 * 2064) = s12; *(bf16x8*)(sdst + 13 * 2064) = s13;
        *(bf16x8*)(sdst + 14 * 2064) = s14; *(bf16x8*)(sdst + 15 * 2064) = s15;
      }
      __syncthreads();

#pragma unroll 8
      for (int kk = 0; kk < 32; ++kk) {
        bf16x8 b  = *(const bf16x8*)(bhp + kk * 32);
        bf16x8 a0 = *(const bf16x8*)(hs + lm * 1032 + kk * 32 + qk);
        bf16x8 a1 = *(const bf16x8*)(hs + (16 + lm) * 1032 + kk * 32 + qk);
        acc0 = mfma16(a0, b, acc0);
        acc1 = mfma16(a1, b, acc1);
      }
    }

    {
      __bf16* hn = (t & 1) ? h0 : h1;
#pragma unroll
      for (int r = 0; r < 4; ++r) {
        const int m0 = r0 + q * 4 + r;
        store_coh_bf16(hn + (size_t)m0 * 1024 + n, tanh_fast(acc0[r] + bias));
        store_coh_bf16(hn + (size_t)(m0 + 16) * 1024 + n, tanh_fast(acc1[r] + bias));
      }
    }
    asm volatile("s_waitcnt vmcnt(0)" ::: "memory");
    __syncthreads();
    if (tid == 0)
      __hip_atomic_fetch_add(ct, 1u, __ATOMIC_RELAXED, __HIP_MEMORY_SCOPE_AGENT);
  }
}

// ---------------------------------------------------------------------------
__global__ __launch_bounds__(256) void k_out(
    const __bf16* __restrict__ hfin,
    const __bf16* __restrict__ whob,
    const float*  __restrict__ bho,
    float* __restrict__ y)
{
  const int tid  = threadIdx.x;
  const int lane = tid & 63;
  const int w    = tid >> 6;
  const int col0 = blockIdx.x * 16;
  const int row0 = w * 32;
  const int lm   = lane & 15;
  const int qk   = (lane >> 4) * 8;

  floatx4 acc0 = {0.f, 0.f, 0.f, 0.f};
  floatx4 acc1 = {0.f, 0.f, 0.f, 0.f};
  const __bf16* bp = whob + (size_t)(col0 + lm) * 1024 + qk;
  const __bf16* a0 = hfin + (size_t)(row0 + lm) * 1024 + qk;
  const __bf16* a1 = a0 + 16 * 1024;
#pragma unroll 8
  for (int kk = 0; kk < 32; ++kk) {
    bf16x8 b = *(const bf16x8*)(bp + kk * 32);
    acc0 = mfma16(*(const bf16x8*)(a0 + kk * 32), b, acc0);
    acc1 = mfma16(*(const bf16x8*)(a1 + kk * 32), b, acc1);
  }
  const int nn = col0 + lm;
  const float bias = bho[nn];
#pragma unroll
  for (int r = 0; r < 4; ++r) {
    const int m0 = row0 + (lane >> 4) * 4 + r;
    const int m1 = m0 + 16;
    y[(size_t)m0 * 512 + nn] = acc0[r] + bias;
    y[(size_t)m1 * 512 + nn] = acc1[r] + bias;
  }
}

extern "C" void kernel_launch(void* const* d_in, const int* in_sizes, int n_in,
                              void* d_out, int out_size, void* d_ws, size_t ws_size,
                              hipStream_t stream) {
  const float* x   = (const float*)d_in[0];
  const float* wih = (const float*)d_in[1];
  const float* bih = (const float*)d_in[2];
  const float* who = (const float*)d_in[3];
  const float* bho = (const float*)d_in[4];
  float* y = (float*)d_out;

  // ---- new path: xp precompute (needs ~273.2 MB workspace)
  const size_t NEED = 268435456ull + 3145728ull + 1048576ull
                    + 262144ull + 262144ull + 512ull;   // 273,154,560
  if (ws_size >= NEED) {
    char* p = (char*)d_ws;
    __bf16* xpb  = (__bf16*)p;                        // 268,435,456 B
    __bf16* wihb = (__bf16*)(p + 268435456ull);       //   3,145,728 B
    __bf16* whob = (__bf16*)(p + 271581184ull);       //   1,048,576 B
    __bf16* h0   = (__bf16*)(p + 272629760ull);       //     262,144 B
    __bf16* h1   = (__bf16*)(p + 272891904ull);       //     262,144 B
    unsigned* cnt = (unsigned*)(p + 273154048ull);    //         512 B

    hipMemsetAsync(cnt, 0, 512, stream);
    k_cvt<<<dim3(512), dim3(256), 0, stream>>>(wih, wihb, 1572864 / 8);
    k_cvt<<<dim3(256), dim3(256), 0, stream>>>(who, whob, 524288 / 8);
    k_xp<<<dim3(4096), dim3(256), 0, stream>>>(x, wihb, xpb);
    k_rnn2<<<dim3(64), dim3(256), 0, stream>>>(xpb, wihb, bih, h0, h1, cnt);
    k_out<<<dim3(32), dim3(256), 0, stream>>>(h0, whob, bho, y);
    return;
  }

  // ---- fallback: previously verified path
  char* p = (char*)d_ws;
  __bf16* xb   = (__bf16*)p;                       // 134,217,728 B
  __bf16* wihb = (__bf16*)(p + 134217728ull);      //   3,145,728 B
  __bf16* whob = (__bf16*)(p + 137363456ull);      //   1,048,576 B
  __bf16* h0   = (__bf16*)(p + 138412032ull);      //     262,144 B
  __bf16* h1   = (__bf16*)(p + 138674176ull);      //     262,144 B
  unsigned* cnt = (unsigned*)(p + 138936320ull);   //         256 B

  hipMemsetAsync(cnt, 0, 256, stream);

  k_cvt<<<dim3(2048), dim3(256), 0, stream>>>(x,   xb,   67108864 / 8);
  k_cvt<<<dim3(512),  dim3(256), 0, stream>>>(wih, wihb, 1572864 / 8);
  k_cvt<<<dim3(256),  dim3(256), 0, stream>>>(who, whob, 524288 / 8);

  k_rnn<<<dim3(64), dim3(256), 0, stream>>>(xb, wihb, bih, h0, h1, cnt);
  k_out<<<dim3(32), dim3(256), 0, stream>>>(h0, whob, bho, y);
}

// Round 6
// 4501.770 us; speedup vs baseline: 1.0687x; 1.0687x over previous
//
#include <hip/hip_runtime.h>
#include <hip/hip_bf16.h>
#include <cstdint>
#include <cstddef>

typedef __attribute__((ext_vector_type(8))) __bf16 bf16x8;
typedef __attribute__((ext_vector_type(4))) __bf16 bf16x4;
typedef __attribute__((ext_vector_type(4))) float floatx4;
typedef __attribute__((ext_vector_type(16))) float floatx16;

__device__ __forceinline__ floatx4 mfma16(bf16x8 a, bf16x8 b, floatx4 c) {
  return __builtin_amdgcn_mfma_f32_16x16x32_bf16(a, b, c, 0, 0, 0);
}
__device__ __forceinline__ floatx16 mfma32(bf16x8 a, bf16x8 b, floatx16 c) {
  return __builtin_amdgcn_mfma_f32_32x32x16_bf16(a, b, c, 0, 0, 0);
}

__device__ __forceinline__ float tanh_fast(float x) {
  float e = __expf(2.0f * x);
  return 1.0f - 2.0f / (e + 1.0f);
}

// Coherent (MALL-level) bf16 store: sc0 sc1 = write-through past L1/L2.
__device__ __forceinline__ void store_coh_bf16(__bf16* p, float f) {
  unsigned v = (unsigned)__builtin_bit_cast(unsigned short, (__bf16)f);
  asm volatile("global_store_short %0, %1, off sc0 sc1" :: "v"(p), "v"(v));
}
__device__ __forceinline__ void store_coh_b128(__bf16* p, bf16x8 v) {
  asm volatile("global_store_dwordx4 %0, %1, off sc0 sc1" :: "v"(p), "v"(v) : "memory");
}
__device__ __forceinline__ void coh_load4(const char* p, bf16x8& a, bf16x8& b,
                                          bf16x8& c, bf16x8& d) {
  asm volatile(
      "global_load_dwordx4 %0, %4, off offset:-4096 sc0 sc1\n\t"
      "global_load_dwordx4 %1, %4, off sc0 sc1\n\t"
      "global_load_dwordx4 %2, %5, off offset:-4096 sc0 sc1\n\t"
      "global_load_dwordx4 %3, %5, off sc0 sc1"
      : "=v"(a), "=v"(b), "=v"(c), "=v"(d)
      : "v"(p), "v"(p + 8192)
      : "memory");
}

// Poll 4 per-wave counters spread across 64B-strided lines; one vmcnt RT.
__device__ __forceinline__ void poll4s(const unsigned* p, unsigned& a, unsigned& b,
                                       unsigned& c, unsigned& d) {
  asm volatile(
      "global_load_dword %0, %4, off sc0 sc1\n\t"
      "global_load_dword %1, %4, off offset:64 sc0 sc1\n\t"
      "global_load_dword %2, %4, off offset:128 sc0 sc1\n\t"
      "global_load_dword %3, %4, off offset:192 sc0 sc1\n\t"
      "s_waitcnt vmcnt(0)"
      : "=v"(a), "=v"(b), "=v"(c), "=v"(d)
      : "v"(p)
      : "memory");
}

__device__ __forceinline__ void coh_wait8(bf16x8& a, bf16x8& b, bf16x8& c, bf16x8& d,
                                          bf16x8& e, bf16x8& f, bf16x8& g, bf16x8& h) {
  asm volatile("s_waitcnt vmcnt(0)"
               : "+v"(a), "+v"(b), "+v"(c), "+v"(d),
                 "+v"(e), "+v"(f), "+v"(g), "+v"(h)
               :
               : "memory");
}
// Counted wait: with 16 staging loads (+ at most xp prefetch + posted signal
// atomic) outstanding, vmcnt(8) guarantees the oldest half (s0..s7) landed.
__device__ __forceinline__ void coh_wait8_vm8(bf16x8& a, bf16x8& b, bf16x8& c, bf16x8& d,
                                              bf16x8& e, bf16x8& f, bf16x8& g, bf16x8& h) {
  asm volatile("s_waitcnt vmcnt(8)"
               : "+v"(a), "+v"(b), "+v"(c), "+v"(d),
                 "+v"(e), "+v"(f), "+v"(g), "+v"(h)
               :
               : "memory");
}

// ---------------------------------------------------------------------------
__global__ __launch_bounds__(256) void k_cvt(const float* __restrict__ src,
                                             __bf16* __restrict__ dst, int n8) {
  int i = blockIdx.x * 256 + threadIdx.x;
  const int stride = gridDim.x * 256;
  for (; i < n8; i += stride) {
    const float4* s = (const float4*)(src + (size_t)i * 8);
    float4 a = s[0], b = s[1];
    bf16x8 v;
    v[0] = (__bf16)a.x; v[1] = (__bf16)a.y; v[2] = (__bf16)a.z; v[3] = (__bf16)a.w;
    v[4] = (__bf16)b.x; v[5] = (__bf16)b.y; v[6] = (__bf16)b.z; v[7] = (__bf16)b.w;
    *(bf16x8*)(dst + (size_t)i * 8) = v;
  }
}

// ---------------------------------------------------------------------------
// k_xp: xp[t][m][n] = sum_i x[m][t][i] * Wx[n][i]  (bf16, t-major).
// ---------------------------------------------------------------------------
__global__ __launch_bounds__(256) void k_xp(
    const float* __restrict__ x,      // [128][1024][512] f32
    const __bf16* __restrict__ wihb,  // [1024][1536] bf16
    __bf16* __restrict__ xp)          // [1024][128][1024] bf16
{
  __shared__ __align__(16) __bf16 xls[32 * 520];
  __shared__ __align__(16) __bf16 st[32 * 72];

  const int tid = threadIdx.x;
  const int t   = blockIdx.x >> 2;
  const int mt  = blockIdx.x & 3;

  {
    const int r = tid >> 3, c = tid & 7;
    const float* xs = x + ((size_t)(mt * 32 + r) * 1024 + t) * 512 + c * 4;
#pragma unroll
    for (int it = 0; it < 16; ++it) {
      float4 v = *(const float4*)(xs + it * 32);
      bf16x4 b;
      b[0] = (__bf16)v.x; b[1] = (__bf16)v.y; b[2] = (__bf16)v.z; b[3] = (__bf16)v.w;
      *(bf16x4*)(xls + r * 520 + it * 32 + c * 4) = b;
    }
  }
  __syncthreads();

  const int lane = tid & 63, w = tid >> 6;
  const int lm = lane & 15, q = lane >> 4, qk = q * 8;

  bf16x8 a0[16], a1[16];
#pragma unroll
  for (int kk = 0; kk < 16; ++kk) {
    a0[kk] = *(const bf16x8*)(xls + lm * 520 + kk * 32 + qk);
    a1[kk] = *(const bf16x8*)(xls + (16 + lm) * 520 + kk * 32 + qk);
  }

  const int row = tid >> 3, ch = tid & 7;
  for (int pass = 0; pass < 16; ++pass) {
    const int n = pass * 64 + w * 16 + lm;
    const __bf16* bp = wihb + (size_t)n * 1536 + qk;
    floatx4 acc0 = {0.f, 0.f, 0.f, 0.f};
    floatx4 acc1 = {0.f, 0.f, 0.f, 0.f};
#pragma unroll
    for (int kk = 0; kk < 16; ++kk) {
      bf16x8 b = *(const bf16x8*)(bp + kk * 32);
      acc0 = mfma16(a0[kk], b, acc0);
      acc1 = mfma16(a1[kk], b, acc1);
    }
    __syncthreads();
#pragma unroll
    for (int r = 0; r < 4; ++r) {
      st[(q * 4 + r) * 72 + w * 16 + lm]      = (__bf16)acc0[r];
      st[(16 + q * 4 + r) * 72 + w * 16 + lm] = (__bf16)acc1[r];
    }
    __syncthreads();
    bf16x8 v = *(const bf16x8*)(st + row * 72 + ch * 8);
    *(bf16x8*)(xp + ((size_t)t * 128 + mt * 32 + row) * 1024 + pass * 64 + ch * 8) = v;
  }
}

// ---------------------------------------------------------------------------
// k_rnn2: xp-fed recurrence (R3-verified structure). 4 groups x 16 col-blocks
// (64 cols), 64 blocks, 1/CU. Wh K-split across waves (mfma32), hs staged
// once per CU per step, cross-wave K-reduction in separate LDS, counted-vmcnt
// staging split, one 16B coherent store per thread.
// Sync protocol (all MALL-coherent, sc0 sc1):
//   - signal: per-wave; lane 0 of wave w adds to ct[w] AFTER vmcnt(0) drain.
//     Counters live on separate 64B lines (stride 16 words) to avoid
//     same-line atomic queueing at MALL.
//   - detect: PER-WAVE. Lane 0 of each wave polls the 4 counters; wave
//     divergence holds the wave; no block barrier between detect and staging.
//     Safety: every wave-signal of step t-1 is posted only after that wave's
//     hs/part reads completed, so a wave that sees all 64 signals may write
//     hs/part immediately.
// Static LDS: 66,048 + 34,816 = 100,864 B (1 block/CU).
// cnt layout: group g, wave w -> word g*64 + w*16 (4KB total fits in 1KB: 4
// groups x 64 words x 4B = 1024 B).
// ---------------------------------------------------------------------------
__global__ __launch_bounds__(256, 1) void k_rnn2(
    const __bf16* __restrict__ xp,      // [1024][128][1024]
    const __bf16* __restrict__ wihb,    // [1024][1536]
    const float*  __restrict__ bih,     // [1024]
    __bf16* __restrict__ h0,
    __bf16* __restrict__ h1,
    unsigned* __restrict__ cnt)
{
  __shared__ __align__(16) __bf16 hs[32 * 1032];    // 66,048 B
  __shared__ __align__(16) float part[4 * 32 * 68]; // 34,816 B

  const int tid  = threadIdx.x;
  const int lane = tid & 63;
  const int w    = tid >> 6;
  const int g    = blockIdx.x >> 4;
  const int cb   = blockIdx.x & 15;
  const int l31  = lane & 31;
  const int l5   = lane >> 5;
  const int r0   = g * 32;
  const int n0   = cb * 64;
  unsigned* ct = cnt + g * 64;          // wave w's counter at ct[w*16]

  // Wh fragments: wave w owns K-slice [w*256, w*256+256), all 64 cols
  bf16x8 wh0[16], wh1[16];
  {
    const __bf16* wp = wihb + (size_t)(n0 + l31) * 1536 + 512 + w * 256 + l5 * 8;
#pragma unroll
    for (int s = 0; s < 16; ++s) {
      wh0[s] = *(const bf16x8*)(wp + s * 16);              // cols n0..n0+31
      wh1[s] = *(const bf16x8*)(wp + 32 * 1536 + s * 16);  // cols n0+32..n0+63
    }
  }

  const int erow = tid >> 3;           // epilogue row 0..31
  const int ec0  = (tid & 7) * 8;      // epilogue col-chunk base
  const floatx4 bia = *(const floatx4*)(bih + n0 + ec0);
  const floatx4 bib = *(const floatx4*)(bih + n0 + ec0 + 4);

  __bf16* sdst = hs + (tid >> 7) * 1032 + (tid & 127) * 8;
  const int koff = w * 256 + l5 * 8;

  for (int t = 0; t < 1024; ++t) {
    // prefetch this step's xp slice (precomputed; valid any time)
    bf16x8 xpv = *(const bf16x8*)(xp + ((size_t)t * 128 + r0 + erow) * 1024 + n0 + ec0);

    floatx16 accA = (floatx16)0.0f;
    floatx16 accB = (floatx16)0.0f;

    if (t > 0) {
      // ---- per-wave detect: lane 0 polls; wave divergence holds the wave
      if (lane == 0) {
        const unsigned target = (unsigned)t * 16u;
        for (;;) {
          unsigned c0, c1, c2, c3;
          poll4s(ct, c0, c1, c2, c3);
          if (c0 >= target && c1 >= target && c2 >= target && c3 >= target)
            break;
          __builtin_amdgcn_s_sleep(1);
        }
      }
      // no barrier: this wave may now stage its portion of h_t

      // stage h_t rows r0..r0+31 -> LDS (coherent, bulk-issued, split drain)
      {
        const __bf16* hc = (t & 1) ? h1 : h0;
        const char* base = (const char*)(hc + (size_t)r0 * 1024) + tid * 16 + 4096;
        bf16x8 s0,s1,s2,s3,s4,s5,s6,s7,s8,s9,s10,s11,s12,s13,s14,s15;
        coh_load4(base,         s0, s1, s2, s3);
        coh_load4(base + 16384, s4, s5, s6, s7);
        coh_load4(base + 32768, s8, s9, s10, s11);
        coh_load4(base + 49152, s12, s13, s14, s15);
        coh_wait8_vm8(s0, s1, s2, s3, s4, s5, s6, s7);   // front half landed
        *(bf16x8*)(sdst +  0 * 2064) = s0;  *(bf16x8*)(sdst +  1 * 2064) = s1;
        *(bf16x8*)(sdst +  2 * 2064) = s2;  *(bf16x8*)(sdst +  3 * 2064) = s3;
        *(bf16x8*)(sdst +  4 * 2064) = s4;  *(bf16x8*)(sdst +  5 * 2064) = s5;
        *(bf16x8*)(sdst +  6 * 2064) = s6;  *(bf16x8*)(sdst +  7 * 2064) = s7;
        coh_wait8(s8, s9, s10, s11, s12, s13, s14, s15); // back half
        *(bf16x8*)(sdst +  8 * 2064) = s8;  *(bf16x8*)(sdst +  9 * 2064) = s9;
        *(bf16x8*)(sdst + 10 * 2064) = s10; *(bf16x8*)(sdst + 11 * 2064) = s11;
        *(bf16x8*)(sdst + 12 * 2064) = s12; *(bf16x8*)(sdst + 13 * 2064) = s13;
        *(bf16x8*)(sdst + 14 * 2064) = s14; *(bf16x8*)(sdst + 15 * 2064) = s15;
      }
      __syncthreads();   // all staging done before any hs read

      // K-split h-matmul: weights in regs, hs read once per CU per step
#pragma unroll
      for (int s = 0; s < 16; ++s) {
        bf16x8 a = *(const bf16x8*)(hs + l31 * 1032 + koff + s * 16);
        accA = mfma32(a, wh0[s], accA);
        accB = mfma32(a, wh1[s], accB);
      }
    }

    // partial sums (separate buffer; prior-step part reads completed before
    // the signals this step's detect observed)
#pragma unroll
    for (int r = 0; r < 16; ++r) {
      const int prow = (r & 3) + 8 * (r >> 2) + 4 * l5;   // C/D row map
      part[(size_t)(w * 32 + prow) * 68 + l31]      = accA[r];
      part[(size_t)(w * 32 + prow) * 68 + 32 + l31] = accB[r];
    }
    __syncthreads();

    // epilogue: reduce 4 partials + xp + bias, tanh, one 16B coherent store
    {
      floatx4 sa = (floatx4)0.0f, sb = (floatx4)0.0f;
#pragma unroll
      for (int w2 = 0; w2 < 4; ++w2) {
        const float* pp = part + (size_t)(w2 * 32 + erow) * 68 + ec0;
        sa += *(const floatx4*)pp;
        sb += *(const floatx4*)(pp + 4);
      }
      bf16x8 res;
#pragma unroll
      for (int j = 0; j < 4; ++j) {
        res[j]     = (__bf16)tanh_fast(sa[j] + bia[j] + (float)xpv[j]);
        res[j + 4] = (__bf16)tanh_fast(sb[j] + bib[j] + (float)xpv[j + 4]);
      }
      __bf16* hn = (t & 1) ? h0 : h1;
      store_coh_b128(hn + (size_t)(r0 + erow) * 1024 + n0 + ec0, res);
    }
    // per-wave signal: drain own coherent stores, then lane 0 increments
    asm volatile("s_waitcnt vmcnt(0)" ::: "memory");
    if (lane == 0)
      __hip_atomic_fetch_add(ct + w * 16, 1u, __ATOMIC_RELAXED, __HIP_MEMORY_SCOPE_AGENT);
  }
  // h_1024 lands in h0 (t=1023 writes hn=h0)
}

// ---------------------------------------------------------------------------
// Fallback (first verified) recurrence kernel — used when ws is small.
// ---------------------------------------------------------------------------
__global__ __launch_bounds__(256) void k_rnn(
    const __bf16* __restrict__ xb,      // [128][1024][512]
    const __bf16* __restrict__ wihb,    // [1024][1536]
    const float*  __restrict__ bih,     // [1024]
    __bf16* __restrict__ h0,
    __bf16* __restrict__ h1,
    unsigned* __restrict__ cnt)
{
  __shared__ __bf16 hs[32 * 1032];

  const int tid  = threadIdx.x;
  const int lane = tid & 63;
  const int w    = tid >> 6;
  const int g    = blockIdx.x >> 4;
  const int cb   = blockIdx.x & 15;
  const int lm   = lane & 15;
  const int q    = lane >> 4;
  const int qk   = q * 8;
  const int wc   = cb * 64 + w * 16;
  const int n    = wc + lm;
  const int r0   = g * 32;

  const __bf16* bxp = wihb + (size_t)n * 1536 + qk;
  const __bf16* bhp = bxp + 512;
  const float bias = bih[n];
  unsigned* ct = cnt + g * 16;

  const __bf16* xr0 = xb + (size_t)(r0 + lm) * 524288 + qk;
  const __bf16* xr1 = xr0 + 16ull * 524288;

  __bf16* sdst = hs + (tid >> 7) * 1032 + (tid & 127) * 8;

  for (int t = 0; t < 1024; ++t) {
    floatx4 acc0 = {0.f, 0.f, 0.f, 0.f};
    floatx4 acc1 = {0.f, 0.f, 0.f, 0.f};

    {
      const __bf16* xa0 = xr0 + (size_t)t * 512;
      const __bf16* xa1 = xr1 + (size_t)t * 512;
#pragma unroll 4
      for (int kk = 0; kk < 16; ++kk) {
        bf16x8 b = *(const bf16x8*)(bxp + kk * 32);
        acc0 = mfma16(*(const bf16x8*)(xa0 + kk * 32), b, acc0);
        acc1 = mfma16(*(const bf16x8*)(xa1 + kk * 32), b, acc1);
      }
    }

    if (t > 0) {
      if (tid == 0) {
        const unsigned target = (unsigned)t * 16u;
        while (__hip_atomic_load(ct, __ATOMIC_RELAXED, __HIP_MEMORY_SCOPE_AGENT) < target)
          __builtin_amdgcn_s_sleep(1);
      }
      __syncthreads();

      {
        const __bf16* hc = (t & 1) ? h1 : h0;
        const char* base = (const char*)(hc + (size_t)r0 * 1024) + tid * 16 + 4096;
        bf16x8 s0,s1,s2,s3,s4,s5,s6,s7,s8,s9,s10,s11,s12,s13,s14,s15;
        coh_load4(base,         s0, s1, s2, s3);
        coh_load4(base + 16384, s4, s5, s6, s7);
        coh_load4(base + 32768, s8, s9, s10, s11);
        coh_load4(base + 49152, s12, s13, s14, s15);
        coh_wait8(s0, s1, s2, s3, s4, s5, s6, s7);
        coh_wait8(s8, s9, s10, s11, s12, s13, s14, s15);
        *(bf16x8*)(sdst +  0 * 2064) = s0;  *(bf16x8*)(sdst +  1 * 2064) = s1;
        *(bf16x8*)(sdst +  2 * 2064) = s2;  *(bf16x8*)(sdst +  3 * 2064) = s3;
        *(bf16x8*)(sdst +  4 * 2064) = s4;  *(bf16x8*)(sdst +  5 * 2064) = s5;
        *(bf16x8*)(sdst +  6 * 2064) = s6;  *(bf16x8*)(sdst +  7 * 2064) = s7;
        *(bf16x8*)(sdst +  8 * 2064) = s8;  *(bf16x8*)(sdst +  9 * 2064) = s9;
        *(bf16x8*)(sdst + 10 * 2064) = s10; *(bf16x8*)(sdst + 11 * 2064) = s11;
        *(bf16x8*)(sdst + 12 * 2064) = s12; *(bf16x8*)(sdst + 13 * 2064) = s13;
        *(bf16x8*)(sdst + 14 * 2064) = s14; *(bf16x8*)(sdst + 15 * 2064) = s15;
      }
      __syncthreads();

#pragma unroll 8
      for (int kk = 0; kk < 32; ++kk) {
        bf16x8 b  = *(const bf16x8*)(bhp + kk * 32);
        bf16x8 a0 = *(const bf16x8*)(hs + lm * 1032 + kk * 32 + qk);
        bf16x8 a1 = *(const bf16x8*)(hs + (16 + lm) * 1032 + kk * 32 + qk);
        acc0 = mfma16(a0, b, acc0);
        acc1 = mfma16(a1, b, acc1);
      }
    }

    {
      __bf16* hn = (t & 1) ? h0 : h1;
#pragma unroll
      for (int r = 0; r < 4; ++r) {
        const int m0 = r0 + q * 4 + r;
        store_coh_bf16(hn + (size_t)m0 * 1024 + n, tanh_fast(acc0[r] + bias));
        store_coh_bf16(hn + (size_t)(m0 + 16) * 1024 + n, tanh_fast(acc1[r] + bias));
      }
    }
    asm volatile("s_waitcnt vmcnt(0)" ::: "memory");
    __syncthreads();
    if (tid == 0)
      __hip_atomic_fetch_add(ct, 1u, __ATOMIC_RELAXED, __HIP_MEMORY_SCOPE_AGENT);
  }
}

// ---------------------------------------------------------------------------
__global__ __launch_bounds__(256) void k_out(
    const __bf16* __restrict__ hfin,
    const __bf16* __restrict__ whob,
    const float*  __restrict__ bho,
    float* __restrict__ y)
{
  const int tid  = threadIdx.x;
  const int lane = tid & 63;
  const int w    = tid >> 6;
  const int col0 = blockIdx.x * 16;
  const int row0 = w * 32;
  const int lm   = lane & 15;
  const int qk   = (lane >> 4) * 8;

  floatx4 acc0 = {0.f, 0.f, 0.f, 0.f};
  floatx4 acc1 = {0.f, 0.f, 0.f, 0.f};
  const __bf16* bp = whob + (size_t)(col0 + lm) * 1024 + qk;
  const __bf16* a0 = hfin + (size_t)(row0 + lm) * 1024 + qk;
  const __bf16* a1 = a0 + 16 * 1024;
#pragma unroll 8
  for (int kk = 0; kk < 32; ++kk) {
    bf16x8 b = *(const bf16x8*)(bp + kk * 32);
    acc0 = mfma16(*(const bf16x8*)(a0 + kk * 32), b, acc0);
    acc1 = mfma16(*(const bf16x8*)(a1 + kk * 32), b, acc1);
  }
  const int nn = col0 + lm;
  const float bias = bho[nn];
#pragma unroll
  for (int r = 0; r < 4; ++r) {
    const int m0 = row0 + (lane >> 4) * 4 + r;
    const int m1 = m0 + 16;
    y[(size_t)m0 * 512 + nn] = acc0[r] + bias;
    y[(size_t)m1 * 512 + nn] = acc1[r] + bias;
  }
}

extern "C" void kernel_launch(void* const* d_in, const int* in_sizes, int n_in,
                              void* d_out, int out_size, void* d_ws, size_t ws_size,
                              hipStream_t stream) {
  const float* x   = (const float*)d_in[0];
  const float* wih = (const float*)d_in[1];
  const float* bih = (const float*)d_in[2];
  const float* who = (const float*)d_in[3];
  const float* bho = (const float*)d_in[4];
  float* y = (float*)d_out;

  // ---- xp-precompute path (needs ~273.2 MB workspace)
  const size_t NEED = 268435456ull + 3145728ull + 1048576ull
                    + 262144ull + 262144ull + 1024ull;   // 273,155,072
  if (ws_size >= NEED) {
    char* p = (char*)d_ws;
    __bf16* xpb  = (__bf16*)p;                        // 268,435,456 B
    __bf16* wihb = (__bf16*)(p + 268435456ull);       //   3,145,728 B
    __bf16* whob = (__bf16*)(p + 271581184ull);       //   1,048,576 B
    __bf16* h0   = (__bf16*)(p + 272629760ull);       //     262,144 B
    __bf16* h1   = (__bf16*)(p + 272891904ull);       //     262,144 B
    unsigned* cnt = (unsigned*)(p + 273154048ull);    //       1,024 B

    hipMemsetAsync(cnt, 0, 1024, stream);
    k_cvt<<<dim3(512), dim3(256), 0, stream>>>(wih, wihb, 1572864 / 8);
    k_cvt<<<dim3(256), dim3(256), 0, stream>>>(who, whob, 524288 / 8);
    k_xp<<<dim3(4096), dim3(256), 0, stream>>>(x, wihb, xpb);
    k_rnn2<<<dim3(64), dim3(256), 0, stream>>>(xpb, wihb, bih, h0, h1, cnt);
    k_out<<<dim3(32), dim3(256), 0, stream>>>(h0, whob, bho, y);
    return;
  }

  // ---- fallback: first verified path
  char* p = (char*)d_ws;
  __bf16* xb   = (__bf16*)p;                       // 134,217,728 B
  __bf16* wihb = (__bf16*)(p + 134217728ull);      //   3,145,728 B
  __bf16* whob = (__bf16*)(p + 137363456ull);      //   1,048,576 B
  __bf16* h0   = (__bf16*)(p + 138412032ull);      //     262,144 B
  __bf16* h1   = (__bf16*)(p + 138674176ull);      //     262,144 B
  unsigned* cnt = (unsigned*)(p + 138936320ull);   //         256 B

  hipMemsetAsync(cnt, 0, 256, stream);

  k_cvt<<<dim3(2048), dim3(256), 0, stream>>>(x,   xb,   67108864 / 8);
  k_cvt<<<dim3(512),  dim3(256), 0, stream>>>(wih, wihb, 1572864 / 8);
  k_cvt<<<dim3(256),  dim3(256), 0, stream>>>(who, whob, 524288 / 8);

  k_rnn<<<dim3(64), dim3(256), 0, stream>>>(xb, wihb, bih, h0, h1, cnt);
  k_out<<<dim3(32), dim3(256), 0, stream>>>(h0, whob, bho, y);
}